// Round 10
// baseline (180.206 us; speedup 1.0000x reference)
//
#include <hip/hip_runtime.h>
#include <hip/hip_fp16.h>

#define RR    80      // max radius (TRUNCATE * MAX_SIGMA + 0.5)
#define WDIM  256     // H == W == 256
#define NSAMP 512
#define RB    64      // band rows per block (keeps T rows = 128B = all 32 banks)
#define NBND  (WDIM / RB)        // 4 bands per sample
#define NBLK  (NSAMP * NBND)     // 2048 blocks, divisible by 8 XCDs
#define UCH   8       // tap chunk

typedef float f32x4 __attribute__((ext_vector_type(4)));

struct alignas(8)  h2x2 { __half2 a, b; };   // f16x4 as two packed half2
struct alignas(16) h8   { __half h[8]; };    // f16x8 tile store

__device__ __forceinline__ int reflect(int q) {
    // symmetric padding; valid for q in [-WDIM, 2*WDIM)
    q = (q < 0) ? (-q - 1) : q;
    return (q >= WDIM) ? (2 * WDIM - 1 - q) : q;
}

// T tile swizzle: XOR on 16B granules (bits 3..5 of half-index), f(c) only.
__device__ __forceinline__ int swz(int c) {
    return (((c >> 2) ^ (c >> 5)) & 7) << 3;
}

// Normalized per-sample weights into wl[192] (zero outside mask). Returns radius.
// Must be called by all 256 threads (contains __syncthreads).
__device__ __forceinline__ int make_weights(int b, const float* __restrict__ sigmas,
                                            const int* __restrict__ steps,
                                            float* wl, float* red) {
    int t = threadIdx.x;
    float sigma = sigmas[steps[b]];
    float radf = floorf(4.0f * sigma + 0.5f);
    if (t < 192) {
        float w = 0.0f;
        if (t < 161) {
            float off = (float)(t - RR);
            if (fabsf(off) <= radf) {
                float z = off / sigma;
                w = expf(-0.5f * z * z);
            }
        }
        wl[t] = w;
    }
    __syncthreads();
    if (t < 64) {
        float s = wl[t] + wl[t + 64] + wl[t + 128];
        #pragma unroll
        for (int o = 32; o > 0; o >>= 1) s += __shfl_down(s, o);
        if (t == 0) red[0] = 1.0f / s;
    }
    __syncthreads();
    float rs = red[0];
    if (t < 161) wl[t] *= rs;
    __syncthreads();
    return (int)radf;
}

// Fused separable blur, packed-f16 math (v_pk_fma_f16 = 2x f32 issue rate).
// Phase V: vertical blur from global f32 (register window, 1-chunk prefetch,
//          cvt_pkrtz at window-insert) -> LDS T[c][i] f16 transposed+swizzled.
// Phase H: horizontal blur straight from f16 T (zero converts in the loop),
//          f32 stores. One barrier total.
__global__ __launch_bounds__(256, 4) void blur_fused(const float* __restrict__ in,
                                                     float* __restrict__ out,
                                                     const float* __restrict__ sigmas,
                                                     const int* __restrict__ steps) {
    __shared__ __half T[WDIM * RB];   // 32 KB: T[c][i] = vblur(x)[r0+i][c]
    __shared__ float wl[192];
    __shared__ float red[1];

    // XCD swizzle: all 4 bands of a sample share one per-XCD L2.
    int bid = blockIdx.x;
    int sw  = (bid & 7) * (NBLK / 8) + (bid >> 3);
    int b   = sw / NBND;
    int r0  = (sw % NBND) * RB;

    int rad = make_weights(b, sigmas, steps, wl, red);
    int nc  = (2 * rad + UCH) / UCH;    // ceil((2*rad+1)/8)

    int wv = threadIdx.x >> 6;          // wave 0..3
    int ln = threadIdx.x & 63;
    const float* inb = in + (size_t)b * WDIM * WDIM;

    // ---------------- Phase V ----------------
    // Wave wv: band rows [16wv, 16wv+16) as two blocks of 8; lane: cols 4ln..4ln+3
    // packed as (c01) -> lo half2, (c23) -> hi half2.
    for (int rbh = 0; rbh < 2; ++rbh) {
        int i0 = (wv << 4) + (rbh << 3);
        int a0 = r0 + i0 - rad;

        __half2 wlo[15], whi[15], aclo[8], achi[8];
        f32x4 nv[8];
        #pragma unroll
        for (int ii = 0; ii < 8; ++ii) {
            aclo[ii] = __float2half2_rn(0.0f);
            achi[ii] = __float2half2_rn(0.0f);
        }
        #pragma unroll
        for (int s = 0; s < 7; ++s) {
            f32x4 v = *(const f32x4*)(inb + (size_t)reflect(a0 + s) * WDIM + 4 * ln);
            wlo[s] = __floats2half2_rn(v[0], v[1]);
            whi[s] = __floats2half2_rn(v[2], v[3]);
        }
        #pragma unroll
        for (int k = 0; k < 8; ++k)
            nv[k] = *(const f32x4*)(inb + (size_t)reflect(a0 + 7 + k) * WDIM + 4 * ln);

        for (int c = 0; c < nc; ++c) {
            // insert prefetched rows (vmcnt wait lands here, ~1 chunk after issue)
            #pragma unroll
            for (int k = 0; k < 8; ++k) {
                wlo[7 + k] = __floats2half2_rn(nv[k][0], nv[k][1]);
                whi[7 + k] = __floats2half2_rn(nv[k][2], nv[k][3]);
            }
            // prefetch next chunk's rows (harmless overshoot on last c)
            #pragma unroll
            for (int k = 0; k < 8; ++k)
                nv[k] = *(const f32x4*)(inb + (size_t)reflect(a0 + 8 * (c + 1) + 7 + k) * WDIM + 4 * ln);
            __half2 ws[UCH];
            #pragma unroll
            for (int t = 0; t < UCH; ++t) ws[t] = __float2half2_rn(wl[RR - rad + 8 * c + t]);
            #pragma unroll
            for (int ii = 0; ii < 8; ++ii) {
                #pragma unroll
                for (int t = 0; t < UCH; ++t) {
                    aclo[ii] = __hfma2(ws[t], wlo[ii + t], aclo[ii]);
                    achi[ii] = __hfma2(ws[t], whi[ii + t], achi[ii]);
                }
            }
            #pragma unroll
            for (int s = 0; s < 7; ++s) { wlo[s] = wlo[s + 8]; whi[s] = whi[s + 8]; }
        }

        // Transposed f16 store into T: col c2=4ln+k gets 8 halfs over ii (16B).
        h8 cols[4];
        #pragma unroll
        for (int ii = 0; ii < 8; ++ii) {
            cols[0].h[ii] = __low2half(aclo[ii]);
            cols[1].h[ii] = __high2half(aclo[ii]);
            cols[2].h[ii] = __low2half(achi[ii]);
            cols[3].h[ii] = __high2half(achi[ii]);
        }
        #pragma unroll
        for (int k = 0; k < 4; ++k) {
            int c2 = 4 * ln + k;
            *(h8*)&T[((c2 << 6) + i0) ^ swz(c2)] = cols[k];
        }
    }
    __syncthreads();

    // ---------------- Phase H ----------------
    // Lane (q=ln>>4, lr=ln&15): rows 4lr..4lr+3 (packed lo=r01, hi=r23),
    // couts c0..c0+7. Window read straight from f16 T — no converts.
    int q  = ln >> 4;
    int lr = ln & 15;
    float* ob = out + (size_t)b * WDIM * WDIM;

    for (int hh = 0; hh < 2; ++hh) {
        int c0 = ((wv << 2) + q + (hh << 4)) << 3;
        int a0 = c0 - rad;

        __half2 wlo[15], whi[15], aclo[8], achi[8];
        #pragma unroll
        for (int ii = 0; ii < 8; ++ii) {
            aclo[ii] = __float2half2_rn(0.0f);
            achi[ii] = __float2half2_rn(0.0f);
        }
        #pragma unroll
        for (int s = 0; s < 7; ++s) {
            int ci = reflect(a0 + s);
            h2x2 p = *(const h2x2*)&T[((ci << 6) + 4 * lr) ^ swz(ci)];
            wlo[s] = p.a; whi[s] = p.b;
        }

        for (int c = 0; c < nc; ++c) {
            #pragma unroll
            for (int s = 7; s < 15; ++s) {
                int ci = reflect(a0 + 8 * c + s);
                h2x2 p = *(const h2x2*)&T[((ci << 6) + 4 * lr) ^ swz(ci)];
                wlo[s] = p.a; whi[s] = p.b;
            }
            __half2 ws[UCH];
            #pragma unroll
            for (int t = 0; t < UCH; ++t) ws[t] = __float2half2_rn(wl[RR - rad + 8 * c + t]);
            #pragma unroll
            for (int ii = 0; ii < 8; ++ii) {
                #pragma unroll
                for (int t = 0; t < UCH; ++t) {
                    aclo[ii] = __hfma2(ws[t], wlo[ii + t], aclo[ii]);
                    achi[ii] = __hfma2(ws[t], whi[ii + t], achi[ii]);
                }
            }
            #pragma unroll
            for (int s = 0; s < 7; ++s) { wlo[s] = wlo[s + 8]; whi[s] = whi[s + 8]; }
        }

        // Store: row r0+4lr+k (k unrolled -> selects fold), cols c0..c0+7, f32.
        #pragma unroll
        for (int k = 0; k < 4; ++k) {
            int r = r0 + 4 * lr + k;
            f32x4 v0, v1;
            #pragma unroll
            for (int ii = 0; ii < 4; ++ii) {
                v0[ii] = (k == 0) ? __low2float(aclo[ii])
                       : (k == 1) ? __high2float(aclo[ii])
                       : (k == 2) ? __low2float(achi[ii])
                       :            __high2float(achi[ii]);
                v1[ii] = (k == 0) ? __low2float(aclo[ii + 4])
                       : (k == 1) ? __high2float(aclo[ii + 4])
                       : (k == 2) ? __low2float(achi[ii + 4])
                       :            __high2float(achi[ii + 4]);
            }
            *(f32x4*)(ob + (size_t)r * WDIM + c0)     = v0;
            *(f32x4*)(ob + (size_t)r * WDIM + c0 + 4) = v1;
        }
    }
}

extern "C" void kernel_launch(void* const* d_in, const int* in_sizes, int n_in,
                              void* d_out, int out_size, void* d_ws, size_t ws_size,
                              hipStream_t stream) {
    const float* x     = (const float*)d_in[0];
    const float* sig   = (const float*)d_in[1];
    const int*   steps = (const int*)d_in[2];
    float* out = (float*)d_out;
    (void)d_ws; (void)ws_size;

    blur_fused<<<NBLK, 256, 0, stream>>>(x, out, sig, steps);
}

// Round 11
// 171.177 us; speedup vs baseline: 1.0527x; 1.0527x over previous
//
#include <hip/hip_runtime.h>

#define RR    80      // max radius (TRUNCATE * MAX_SIGMA + 0.5)
#define WDIM  256     // H == W == 256
#define NSAMP 512
#define RB    64      // band rows per block-task
#define NBND  (WDIM / RB)        // 4 bands per sample
#define NBAND (NSAMP * NBND)     // 2048 band tasks
#define UCH   8       // tap chunk
#define QOFF  16      // ints: q[0]=pop counter, q[QOFF..] = sorted band list

typedef float    f32x4 __attribute__((ext_vector_type(4)));
typedef _Float16 f16x4 __attribute__((ext_vector_type(4)));
typedef _Float16 f16x8 __attribute__((ext_vector_type(8)));

__device__ __forceinline__ int reflect(int q) {
    // symmetric padding; valid for q in [-WDIM, 2*WDIM)
    q = (q < 0) ? (-q - 1) : q;
    return (q >= WDIM) ? (2 * WDIM - 1 - q) : q;
}

// T tile swizzle: XOR on 16B granules (bits 3..5 of half-index), f(c) only.
__device__ __forceinline__ int swz(int c) {
    return (((c >> 2) ^ (c >> 5)) & 7) << 3;
}

__device__ __forceinline__ f32x4 h4_to_f32(f16x4 h) {
    f32x4 v;
    v[0] = (float)h[0]; v[1] = (float)h[1]; v[2] = (float)h[2]; v[3] = (float)h[3];
    return v;
}

// Normalized per-sample weights into wl[192] (zero outside mask). Returns radius.
// Must be called by all 256 threads (contains __syncthreads).
__device__ __forceinline__ int make_weights(int b, const float* __restrict__ sigmas,
                                            const int* __restrict__ steps,
                                            float* wl, float* red) {
    int t = threadIdx.x;
    float sigma = sigmas[steps[b]];
    float radf = floorf(4.0f * sigma + 0.5f);
    if (t < 192) {
        float w = 0.0f;
        if (t < 161) {
            float off = (float)(t - RR);
            if (fabsf(off) <= radf) {
                float z = off / sigma;
                w = expf(-0.5f * z * z);
            }
        }
        wl[t] = w;
    }
    __syncthreads();
    if (t < 64) {
        float s = wl[t] + wl[t + 64] + wl[t + 128];
        #pragma unroll
        for (int o = 32; o > 0; o >>= 1) s += __shfl_down(s, o);
        if (t == 0) red[0] = 1.0f / s;
    }
    __syncthreads();
    float rs = red[0];
    if (t < 161) wl[t] *= rs;
    __syncthreads();
    return (int)radf;
}

// LPT queue builder: 1 block, 256 threads. Counting-sorts the 2048 bands by
// descending chunk-count nc into q[QOFF..]; zeroes the pop counter q[0].
// Rewrites ALL state every call (harness does not re-poison d_ws).
__global__ void build_queue(const float* __restrict__ sigmas,
                            const int* __restrict__ steps,
                            int* __restrict__ q) {
    __shared__ int hist[32];
    __shared__ int base[32];
    int t = threadIdx.x;
    if (t < 32) hist[t] = 0;
    __syncthreads();
    int ncs[2];
    #pragma unroll
    for (int k = 0; k < 2; ++k) {
        int s = t + 256 * k;
        float sigma = sigmas[steps[s]];
        int rad = (int)floorf(4.0f * sigma + 0.5f);
        ncs[k] = (2 * rad + UCH) / UCH;          // 1..21
        atomicAdd(&hist[ncs[k]], 1);
    }
    __syncthreads();
    if (t == 0) {
        q[0] = 0;
        int acc = 0;
        for (int bin = 31; bin >= 0; --bin) { base[bin] = acc; acc += hist[bin]; }
    }
    __syncthreads();
    #pragma unroll
    for (int k = 0; k < 2; ++k) {
        int s = t + 256 * k;
        int pos = atomicAdd(&base[ncs[k]], 1);   // sample slot within its bin
        #pragma unroll
        for (int j = 0; j < 4; ++j)
            q[QOFF + 4 * pos + j] = (s << 2) | j;   // 4 bands kept adjacent
    }
}

// Fused separable blur; DYN: persistent blocks popping LPT-sorted band tasks.
// Per band: Phase V (vertical blur from global f32, register window, 1-chunk
// prefetch) -> LDS T[c][i] f16 transposed+swizzled; Phase H (horizontal blur
// from T) -> f32 out. One barrier between phases.
template <bool DYN>
__global__ __launch_bounds__(256, 4) void blur_fused(const float* __restrict__ in,
                                                     float* __restrict__ out,
                                                     const float* __restrict__ sigmas,
                                                     const int* __restrict__ steps,
                                                     int* __restrict__ q) {
    __shared__ _Float16 T[WDIM * RB];   // 32 KB: T[c][i] = vblur(x)[r0+i][c]
    __shared__ float wl[192];
    __shared__ float red[1];
    __shared__ int cur;

    int wv = threadIdx.x >> 6;          // wave 0..3
    int ln = threadIdx.x & 63;

    while (true) {
        int e;
        if constexpr (DYN) {
            if (threadIdx.x == 0) cur = atomicAdd(&q[0], 1);
            __syncthreads();
            int i = cur;                 // uniform
            if (i >= NBAND) return;
            e = q[QOFF + i];
        } else {
            int bid = blockIdx.x;        // XCD swizzle for static fallback
            e = (bid & 7) * (NBAND / 8) + (bid >> 3);
        }
        int b  = e >> 2;
        int r0 = (e & 3) * RB;

        int rad = make_weights(b, sigmas, steps, wl, red);
        int nc  = (2 * rad + UCH) / UCH;
        const float* inb = in + (size_t)b * WDIM * WDIM;

        // ---------------- Phase V ----------------
        // Wave wv: band rows [16wv,16wv+16) as two blocks of 8; lane: cols 4ln..4ln+3.
        for (int rbh = 0; rbh < 2; ++rbh) {
            int i0 = (wv << 4) + (rbh << 3);
            int a0 = r0 + i0 - rad;

            f32x4 w15[15], nv[8], acc[8];
            #pragma unroll
            for (int ii = 0; ii < 8; ++ii) acc[ii] = (f32x4)0.0f;
            #pragma unroll
            for (int s = 0; s < 7; ++s)
                w15[s] = *(const f32x4*)(inb + (size_t)reflect(a0 + s) * WDIM + 4 * ln);
            #pragma unroll
            for (int k = 0; k < 8; ++k)
                nv[k] = *(const f32x4*)(inb + (size_t)reflect(a0 + 7 + k) * WDIM + 4 * ln);

            for (int c = 0; c < nc; ++c) {
                #pragma unroll
                for (int k = 0; k < 8; ++k) w15[7 + k] = nv[k];
                // prefetch next chunk (consumed next iter; overshoot harmless)
                #pragma unroll
                for (int k = 0; k < 8; ++k)
                    nv[k] = *(const f32x4*)(inb + (size_t)reflect(a0 + 8 * (c + 1) + 7 + k) * WDIM + 4 * ln);
                float wreg[UCH];
                #pragma unroll
                for (int t = 0; t < UCH; ++t) wreg[t] = wl[RR - rad + 8 * c + t];
                #pragma unroll
                for (int ii = 0; ii < 8; ++ii) {
                    #pragma unroll
                    for (int t = 0; t < UCH; ++t)
                        acc[ii] += wreg[t] * w15[ii + t];
                }
                #pragma unroll
                for (int s = 0; s < 7; ++s) w15[s] = w15[s + 8];
            }

            // Transposed f16 store into T: col c2=4ln+k gets 8 halfs (16B, swizzled).
            #pragma unroll
            for (int k = 0; k < 4; ++k) {
                int c2 = 4 * ln + k;
                f16x8 v;
                #pragma unroll
                for (int ii = 0; ii < 8; ++ii) v[ii] = (_Float16)acc[ii][k];
                *(f16x8*)&T[((c2 << 6) + i0) ^ swz(c2)] = v;
            }
        }
        __syncthreads();

        // ---------------- Phase H ----------------
        // Lane (qq=ln>>4, lr=ln&15): rows 4lr..4lr+3, couts c0..c0+7.
        int qq = ln >> 4;
        int lr = ln & 15;
        float* ob = out + (size_t)b * WDIM * WDIM;

        for (int hh = 0; hh < 2; ++hh) {
            int c0 = ((wv << 2) + qq + (hh << 4)) << 3;
            int a0 = c0 - rad;

            f32x4 w15[15], acc[8];
            #pragma unroll
            for (int ii = 0; ii < 8; ++ii) acc[ii] = (f32x4)0.0f;
            #pragma unroll
            for (int s = 0; s < 7; ++s) {
                int ci = reflect(a0 + s);
                w15[s] = h4_to_f32(*(const f16x4*)&T[((ci << 6) + 4 * lr) ^ swz(ci)]);
            }

            for (int c = 0; c < nc; ++c) {
                #pragma unroll
                for (int s = 7; s < 15; ++s) {
                    int ci = reflect(a0 + 8 * c + s);
                    w15[s] = h4_to_f32(*(const f16x4*)&T[((ci << 6) + 4 * lr) ^ swz(ci)]);
                }
                float wreg[UCH];
                #pragma unroll
                for (int t = 0; t < UCH; ++t) wreg[t] = wl[RR - rad + 8 * c + t];
                #pragma unroll
                for (int ii = 0; ii < 8; ++ii) {
                    #pragma unroll
                    for (int t = 0; t < UCH; ++t)
                        acc[ii] += wreg[t] * w15[ii + t];
                }
                #pragma unroll
                for (int s = 0; s < 7; ++s) w15[s] = w15[s + 8];
            }

            #pragma unroll
            for (int k = 0; k < 4; ++k) {
                int r = r0 + 4 * lr + k;
                f32x4 v0, v1;
                v0[0] = acc[0][k]; v0[1] = acc[1][k]; v0[2] = acc[2][k]; v0[3] = acc[3][k];
                v1[0] = acc[4][k]; v1[1] = acc[5][k]; v1[2] = acc[6][k]; v1[3] = acc[7][k];
                *(f32x4*)(ob + (size_t)r * WDIM + c0)     = v0;
                *(f32x4*)(ob + (size_t)r * WDIM + c0 + 4) = v1;
            }
        }

        if constexpr (!DYN) return;
        __syncthreads();   // protect T, wl, cur before next pop
    }
}

extern "C" void kernel_launch(void* const* d_in, const int* in_sizes, int n_in,
                              void* d_out, int out_size, void* d_ws, size_t ws_size,
                              hipStream_t stream) {
    const float* x     = (const float*)d_in[0];
    const float* sig   = (const float*)d_in[1];
    const int*   steps = (const int*)d_in[2];
    float* out = (float*)d_out;

    const size_t need = (QOFF + NBAND) * sizeof(int);
    if (ws_size >= need) {
        int* q = (int*)d_ws;
        build_queue<<<1, 256, 0, stream>>>(sig, steps, q);
        blur_fused<true><<<1024, 256, 0, stream>>>(x, out, sig, steps, q);
    } else {
        blur_fused<false><<<NBAND, 256, 0, stream>>>(x, out, sig, steps, nullptr);
    }
}

// Round 12
// 139.625 us; speedup vs baseline: 1.2906x; 1.2260x over previous
//
#include <hip/hip_runtime.h>

#define RR    80      // max radius (TRUNCATE * MAX_SIGMA + 0.5)
#define WDIM  256     // H == W == 256
#define NSAMP 512
#define RB    64      // band rows per block-task
#define NBND  (WDIM / RB)        // 4 bands per sample
#define NBAND (NSAMP * NBND)     // 2048 band tasks
#define QOFF  16      // ints; q[QOFF..] = static task table (indexed by blockIdx)

typedef float    f32x4 __attribute__((ext_vector_type(4)));
typedef _Float16 f16x4 __attribute__((ext_vector_type(4)));
typedef _Float16 f16x8 __attribute__((ext_vector_type(8)));

__device__ __forceinline__ int reflect(int q) {
    // symmetric padding; valid for q in [-WDIM, 2*WDIM)
    q = (q < 0) ? (-q - 1) : q;
    return (q >= WDIM) ? (2 * WDIM - 1 - q) : q;
}

// T tile swizzle: XOR on 16B granules (bits 3..5 of half-index), f(c) only.
__device__ __forceinline__ int swz(int c) {
    return (((c >> 2) ^ (c >> 5)) & 7) << 3;
}

__device__ __forceinline__ f32x4 h4_to_f32(f16x4 h) {
    f32x4 v;
    v[0] = (float)h[0]; v[1] = (float)h[1]; v[2] = (float)h[2]; v[3] = (float)h[3];
    return v;
}

// Normalized per-sample weights, zero-padded: wl[8+i] = w[i] for i in [0,160],
// wl[t]=0 elsewhere (t<192). Scatter loops index i in [-8,183] freely.
// Returns radius. Called by all 256 threads (contains __syncthreads).
__device__ __forceinline__ int make_weights(int b, const float* __restrict__ sigmas,
                                            const int* __restrict__ steps,
                                            float* wl, float* red) {
    int t = threadIdx.x;
    float sigma = sigmas[steps[b]];
    float radf = floorf(4.0f * sigma + 0.5f);
    if (t < 192) {
        int i = t - 8;
        float w = 0.0f;
        if (i >= 0 && i <= 160) {
            float off = (float)(i - RR);
            if (fabsf(off) <= radf) {
                float z = off / sigma;
                w = expf(-0.5f * z * z);
            }
        }
        wl[t] = w;
    }
    __syncthreads();
    if (t < 64) {
        float s = wl[t] + wl[t + 64] + wl[t + 128];
        #pragma unroll
        for (int o = 32; o > 0; o >>= 1) s += __shfl_down(s, o);
        if (t == 0) red[0] = 1.0f / s;
    }
    __syncthreads();
    float rs = red[0];
    if (t < 192) wl[t] *= rs;
    __syncthreads();
    return (int)radf;
}

// Striped-LPT static queue: counting-sort samples by descending work; rank r ->
// XCD r%8 (balance), heavy-first within XCD (LPT), a sample's 4 bands on
// consecutive slots of the same XCD (L2 halo locality). bid = 8*j + xcd.
__global__ void build_queue(const float* __restrict__ sigmas,
                            const int* __restrict__ steps,
                            int* __restrict__ q) {
    __shared__ int hist[32];
    __shared__ int base[32];
    int t = threadIdx.x;
    if (t < 32) hist[t] = 0;
    __syncthreads();
    int nb2[2];
    #pragma unroll
    for (int k = 0; k < 2; ++k) {
        int s = t + 256 * k;
        float sigma = sigmas[steps[s]];
        int rad = (int)floorf(4.0f * sigma + 0.5f);
        nb2[k] = (2 * rad + 15) >> 3;            // octs: 2..21
        atomicAdd(&hist[nb2[k]], 1);
    }
    __syncthreads();
    if (t == 0) {
        int acc = 0;
        for (int bin = 31; bin >= 0; --bin) { base[bin] = acc; acc += hist[bin]; }
    }
    __syncthreads();
    #pragma unroll
    for (int k = 0; k < 2; ++k) {
        int s = t + 256 * k;
        int r = atomicAdd(&base[nb2[k]], 1);     // global rank, heavy bins first
        int x = r & 7;                           // XCD
        int p = r >> 3;                          // sample slot within XCD
        #pragma unroll
        for (int jb = 0; jb < 4; ++jb)
            q[QOFF + (((p << 2) + jb) << 3) + x] = (s << 2) | jb;
    }
}

// Fused separable blur, scatter-form: block = one (sample, 64-row band) task.
// Phase V: for each input row (lane-uniform), acc[ii] += w[s-ii]*row — no
// register window, 8 static in-flight rows pipeline the global loads.
// Result -> LDS T[c][i] f16 transposed+swizzled. Phase H: same scatter from T.
template <bool QUEUED>
__global__ __launch_bounds__(256, 4) void blur_fused(const float* __restrict__ in,
                                                     float* __restrict__ out,
                                                     const float* __restrict__ sigmas,
                                                     const int* __restrict__ steps,
                                                     const int* __restrict__ q) {
    __shared__ _Float16 T[WDIM * RB];   // 32 KB: T[c][i] = vblur(x)[r0+i][c]
    __shared__ float wl[192];
    __shared__ float red[1];

    int e;
    if constexpr (QUEUED) {
        e = q[QOFF + blockIdx.x];       // uniform (s_load)
    } else {
        int bid = blockIdx.x;           // fallback: XCD-contiguous static
        e = (bid & 7) * (NBAND / 8) + (bid >> 3);
    }
    int b  = e >> 2;
    int r0 = (e & 3) * RB;

    int rad = make_weights(b, sigmas, steps, wl, red);
    int nb  = (2 * rad + 15) >> 3;      // octs covering span = 2*rad+8
    int wv  = threadIdx.x >> 6;
    int ln  = threadIdx.x & 63;
    const float* inb = in + (size_t)b * WDIM * WDIM;

    // ---------------- Phase V ----------------
    // Wave wv: band rows [16wv,16wv+16) as two blocks of 8; lane: cols 4ln..4ln+3.
    for (int rbh = 0; rbh < 2; ++rbh) {
        int i0    = (wv << 4) + (rbh << 3);
        int arow0 = r0 + i0 - rad;
        int wb0   = 81 - rad;            // wl idx for (sb=0, m=0)

        f32x4 acc[8], infl[8];
        #pragma unroll
        for (int ii = 0; ii < 8; ++ii) acc[ii] = (f32x4)0.0f;
        #pragma unroll
        for (int k = 0; k < 8; ++k)
            infl[k] = *(const f32x4*)(inb + (size_t)reflect(arow0 + k) * WDIM + 4 * ln);

        for (int ob = 0; ob < nb; ++ob) {
            int sb = ob << 3;
            float wv8[15];
            #pragma unroll
            for (int m = 0; m < 15; ++m) wv8[m] = wl[wb0 + sb + m];  // broadcast
            #pragma unroll
            for (int k = 0; k < 8; ++k) {
                f32x4 row = infl[k];
                infl[k] = *(const f32x4*)(inb + (size_t)reflect(arow0 + sb + 8 + k) * WDIM + 4 * ln);
                #pragma unroll
                for (int ii = 0; ii < 8; ++ii)
                    acc[ii] += wv8[k - ii + 7] * row;   // w[s-ii], zero-padded
            }
        }

        // Transposed f16 store into T: col c2=4ln+k gets 8 halfs (16B, swizzled).
        #pragma unroll
        for (int k = 0; k < 4; ++k) {
            int c2 = 4 * ln + k;
            f16x8 v;
            #pragma unroll
            for (int ii = 0; ii < 8; ++ii) v[ii] = (_Float16)acc[ii][k];
            *(f16x8*)&T[((c2 << 6) + i0) ^ swz(c2)] = v;
        }
    }
    __syncthreads();

    // ---------------- Phase H ----------------
    // Lane (qq=ln>>4, lr=ln&15): rows 4lr..4lr+3 (f32x4 fold), couts c0..c0+7.
    int qq = ln >> 4;
    int lr = ln & 15;
    float* ob = out + (size_t)b * WDIM * WDIM;

    for (int hh = 0; hh < 2; ++hh) {
        int c0    = ((wv << 2) + qq + (hh << 4)) << 3;
        int acol0 = c0 - rad;
        int wb0   = 81 - rad;

        f32x4 acc[8];
        #pragma unroll
        for (int jj = 0; jj < 8; ++jj) acc[jj] = (f32x4)0.0f;

        for (int obk = 0; obk < nb; ++obk) {
            int sb = obk << 3;
            float wv8[15];
            #pragma unroll
            for (int m = 0; m < 15; ++m) wv8[m] = wl[wb0 + sb + m];
            f16x4 cv[8];
            #pragma unroll
            for (int k = 0; k < 8; ++k) {
                int ci = reflect(acol0 + sb + k);
                cv[k] = *(const f16x4*)&T[((ci << 6) + 4 * lr) ^ swz(ci)];
            }
            #pragma unroll
            for (int k = 0; k < 8; ++k) {
                f32x4 col = h4_to_f32(cv[k]);
                #pragma unroll
                for (int jj = 0; jj < 8; ++jj)
                    acc[jj] += wv8[k - jj + 7] * col;
            }
        }

        #pragma unroll
        for (int k = 0; k < 4; ++k) {
            int r = r0 + 4 * lr + k;
            f32x4 v0, v1;
            v0[0] = acc[0][k]; v0[1] = acc[1][k]; v0[2] = acc[2][k]; v0[3] = acc[3][k];
            v1[0] = acc[4][k]; v1[1] = acc[5][k]; v1[2] = acc[6][k]; v1[3] = acc[7][k];
            *(f32x4*)(ob + (size_t)r * WDIM + c0)     = v0;
            *(f32x4*)(ob + (size_t)r * WDIM + c0 + 4) = v1;
        }
    }
}

extern "C" void kernel_launch(void* const* d_in, const int* in_sizes, int n_in,
                              void* d_out, int out_size, void* d_ws, size_t ws_size,
                              hipStream_t stream) {
    const float* x     = (const float*)d_in[0];
    const float* sig   = (const float*)d_in[1];
    const int*   steps = (const int*)d_in[2];
    float* out = (float*)d_out;

    const size_t need = (QOFF + NBAND) * sizeof(int);
    if (ws_size >= need) {
        int* q = (int*)d_ws;
        build_queue<<<1, 256, 0, stream>>>(sig, steps, q);
        blur_fused<true><<<NBAND, 256, 0, stream>>>(x, out, sig, steps, q);
    } else {
        blur_fused<false><<<NBAND, 256, 0, stream>>>(x, out, sig, steps, nullptr);
    }
}

// Round 13
// 117.983 us; speedup vs baseline: 1.5274x; 1.1834x over previous
//
#include <hip/hip_runtime.h>

#define WDIM  256
#define NSAMP 512
#define NSIG  32
#define RB    64                 // band rows per block-task
#define NBND  4                  // bands per sample
#define NBAND 2048
#define QOFF  16                 // ints; queue table q[QOFF..]
#define XS    40                 // XT row stride in halfs (80B: aligned + uniform banks)
#define WOFF  65536              // byte offset of W matrices inside d_ws

typedef float    f32x4 __attribute__((ext_vector_type(4)));
typedef _Float16 f16x2 __attribute__((ext_vector_type(2)));
typedef _Float16 f16x8 __attribute__((ext_vector_type(8)));

__device__ __forceinline__ int reflect(int q) {
    q = (q < 0) ? (-q - 1) : q;
    return (q >= WDIM) ? (2 * WDIM - 1 - q) : q;
}

// ---- kernel 1: build 32 reflect-folded banded weight matrices (f16) ----
// W_s[i][r] = wz(r-i) + wz(-r-1-i) + wz(511-r-i), wz = masked+normalized gaussian.
__global__ __launch_bounds__(256) void build_w(const float* __restrict__ sigmas,
                                               _Float16* __restrict__ Wg) {
    __shared__ float wl[161];
    __shared__ float red;
    int s = blockIdx.x, t = threadIdx.x;
    float sigma = sigmas[s];
    float radf = floorf(4.0f * sigma + 0.5f);
    if (t < 161) {
        float off = (float)(t - 80);
        float w = 0.0f;
        if (fabsf(off) <= radf) { float z = off / sigma; w = expf(-0.5f * z * z); }
        wl[t] = w;
    }
    __syncthreads();
    if (t < 64) {
        float v = wl[t] + wl[t + 64] + (t < 33 ? wl[t + 128] : 0.0f);
        #pragma unroll
        for (int o = 32; o > 0; o >>= 1) v += __shfl_down(v, o);
        if (t == 0) red = 1.0f / v;
    }
    __syncthreads();
    float rs = red;
    int i = t;
    _Float16* wrow = Wg + ((size_t)s << 16) + (i << 8);
    for (int rq = 0; rq < 32; ++rq) {
        f16x8 v;
        #pragma unroll
        for (int j = 0; j < 8; ++j) {
            int r = rq * 8 + j;
            int d1 = r - i, d2 = -r - 1 - i, d3 = 511 - r - i;
            float w = 0.0f;
            if (d1 >= -80 && d1 <= 80) w += wl[d1 + 80];
            if (d2 >= -80)             w += wl[d2 + 80];   // d2 <= -1 always
            if (d3 <= 80)              w += wl[d3 + 80];   // d3 >= 1 always
            v[j] = (_Float16)(w * rs);
        }
        *(f16x8*)(wrow + rq * 8) = v;
    }
}

// ---- kernel 2: striped-LPT static queue (same as r12: balance + locality) ----
__global__ void build_queue(const float* __restrict__ sigmas,
                            const int* __restrict__ steps,
                            int* __restrict__ q) {
    __shared__ int hist[32];
    __shared__ int base[32];
    int t = threadIdx.x;
    if (t < 32) hist[t] = 0;
    __syncthreads();
    int nb2[2];
    #pragma unroll
    for (int k = 0; k < 2; ++k) {
        int s = t + 256 * k;
        float sigma = sigmas[steps[s]];
        int rad = (int)floorf(4.0f * sigma + 0.5f);
        nb2[k] = (2 * rad + 15) >> 3;
        atomicAdd(&hist[nb2[k]], 1);
    }
    __syncthreads();
    if (t == 0) {
        int acc = 0;
        for (int bin = 31; bin >= 0; --bin) { base[bin] = acc; acc += hist[bin]; }
    }
    __syncthreads();
    #pragma unroll
    for (int k = 0; k < 2; ++k) {
        int s = t + 256 * k;
        int r = atomicAdd(&base[nb2[k]], 1);
        int x = r & 7;
        int p = r >> 3;
        #pragma unroll
        for (int jb = 0; jb < 4; ++jb)
            q[QOFF + (((p << 2) + jb) << 3) + x] = (s << 2) | jb;
    }
}

// ---- kernel 3: fused MFMA blur. Block = (sample, 64-row band). ----
// Phase V: Y = W_band X via mfma_f32_16x16x32_f16 (A=W global, B=X^T LDS tile)
// Phase H: Z = Y W^T (A=Y swizzled LDS, B=W rows global), f32 out.
template <bool QUEUED>
__global__ __launch_bounds__(256, 3) void blur_mfma(const float* __restrict__ in,
                                                    float* __restrict__ out,
                                                    const float* __restrict__ sigmas,
                                                    const int* __restrict__ steps,
                                                    const int* __restrict__ q,
                                                    const _Float16* __restrict__ Wg) {
    __shared__ alignas(16) _Float16 XT[WDIM * XS];    // X^T K-tile: XT[c*XS + k], 20KB
    __shared__ alignas(16) _Float16 YL[RB * WDIM];    // Y[i][c] swizzled, 32KB

    int e;
    if constexpr (QUEUED) e = q[QOFF + blockIdx.x];
    else { int bid = blockIdx.x; e = (bid & 7) * (NBAND / 8) + (bid >> 3); }
    int b  = e >> 2;
    int r0 = (e & 3) * RB;

    int s = steps[b];
    float sigma = sigmas[s];
    int rad = (int)floorf(4.0f * sigma + 0.5f);
    const _Float16* Wm = Wg + ((size_t)s << 16);
    const float*    Xb = in + ((size_t)b << 16);

    int ln = threadIdx.x & 63, wv = threadIdx.x >> 6;
    int lm = ln & 15, lq = ln >> 4;       // MFMA fragment row/col, k-group
    int sr2 = (threadIdx.x & 15) * 2;     // staging: k-row pair
    int sc0 = (threadIdx.x >> 4) * 16;    // staging: col range

    // ---------------- Phase V: Y[i][c] = sum_r W[r0+i][r] X[r][c] ----------------
    f32x4 acc[4][4];
    #pragma unroll
    for (int mt = 0; mt < 4; ++mt)
        #pragma unroll
        for (int nt = 0; nt < 4; ++nt) acc[mt][nt] = (f32x4)0.0f;

    int kt0 = max(0, r0 - rad) >> 5;
    int kt1 = min(WDIM - 1, r0 + RB - 1 + rad) >> 5;

    for (int kt = kt0; kt <= kt1; ++kt) {
        // stage X^T tile: rows kt*32..+31 (f32, coalesced 2-row/16-col per thread)
        {
            const float* xp = Xb + (size_t)((kt << 5) + sr2) * WDIM + sc0;
            f32x4 A[4], B[4];
            #pragma unroll
            for (int u = 0; u < 4; ++u) {
                A[u] = *(const f32x4*)(xp + 4 * u);
                B[u] = *(const f32x4*)(xp + WDIM + 4 * u);
            }
            #pragma unroll
            for (int u = 0; u < 4; ++u)
                #pragma unroll
                for (int v = 0; v < 4; ++v) {
                    f16x2 p; p[0] = (_Float16)A[u][v]; p[1] = (_Float16)B[u][v];
                    *(f16x2*)&XT[(sc0 + 4 * u + v) * XS + sr2] = p;
                }
        }
        // A-frags from global W (issued before barrier, consumed after)
        f16x8 af[4];
        #pragma unroll
        for (int mt = 0; mt < 4; ++mt)
            af[mt] = *(const f16x8*)(Wm + (size_t)(r0 + mt * 16 + lm) * WDIM + (kt << 5) + lq * 8);
        __syncthreads();
        f16x8 bf[4];
        #pragma unroll
        for (int nt = 0; nt < 4; ++nt)
            bf[nt] = *(const f16x8*)&XT[(wv * 64 + nt * 16 + lm) * XS + lq * 8];
        #pragma unroll
        for (int mt = 0; mt < 4; ++mt)
            #pragma unroll
            for (int nt = 0; nt < 4; ++nt)
                acc[mt][nt] = __builtin_amdgcn_mfma_f32_16x16x32_f16(af[mt], bf[nt], acc[mt][nt], 0, 0, 0);
        __syncthreads();   // also guards next stage overwrite
    }

    // write Y to swizzled LDS: D layout row=(lq*4+g), col=lm per 16x16 tile
    #pragma unroll
    for (int mt = 0; mt < 4; ++mt)
        #pragma unroll
        for (int nt = 0; nt < 4; ++nt)
            #pragma unroll
            for (int g = 0; g < 4; ++g) {
                int i = mt * 16 + lq * 4 + g;
                int c = wv * 64 + nt * 16 + lm;
                YL[(i << 8) + (c ^ ((i & 7) << 3))] = (_Float16)acc[mt][nt][g];
            }
    __syncthreads();

    // ---------------- Phase H: Z[i][j] = sum_c Y[i][c] W[j][c] ----------------
    f32x4 hac[4][4];
    #pragma unroll
    for (int mt = 0; mt < 4; ++mt)
        #pragma unroll
        for (int nt = 0; nt < 4; ++nt) hac[mt][nt] = (f32x4)0.0f;

    int jlo = wv * 64;
    int hk0 = max(0, jlo - rad) >> 5;
    int hk1 = min(WDIM - 1, jlo + 63 + rad) >> 5;

    for (int kt = hk0; kt <= hk1; ++kt) {
        f16x8 af[4], bf[4];
        #pragma unroll
        for (int mt = 0; mt < 4; ++mt) {
            int i = mt * 16 + lm;
            int c0 = (kt << 5) + lq * 8;
            af[mt] = *(const f16x8*)&YL[(i << 8) + (c0 ^ ((i & 7) << 3))];
        }
        #pragma unroll
        for (int nt = 0; nt < 4; ++nt)
            bf[nt] = *(const f16x8*)(Wm + (size_t)(jlo + nt * 16 + lm) * WDIM + (kt << 5) + lq * 8);
        #pragma unroll
        for (int mt = 0; mt < 4; ++mt)
            #pragma unroll
            for (int nt = 0; nt < 4; ++nt)
                hac[mt][nt] = __builtin_amdgcn_mfma_f32_16x16x32_f16(af[mt], bf[nt], hac[mt][nt], 0, 0, 0);
    }

    float* ob = out + ((size_t)b << 16);
    #pragma unroll
    for (int mt = 0; mt < 4; ++mt)
        #pragma unroll
        for (int nt = 0; nt < 4; ++nt)
            #pragma unroll
            for (int g = 0; g < 4; ++g)
                ob[(size_t)(r0 + mt * 16 + lq * 4 + g) * WDIM + jlo + nt * 16 + lm] = hac[mt][nt][g];
}

// ---------- fallback path (only if ws too small; needs no workspace) ----------
__device__ __forceinline__ int make_weights161(int b, const float* __restrict__ sigmas,
                                               const int* __restrict__ steps,
                                               float* wl, float* red) {
    int t = threadIdx.x;
    float sigma = sigmas[steps[b]];
    float radf = floorf(4.0f * sigma + 0.5f);
    if (t < 192) {
        float w = 0.0f;
        if (t < 161) {
            float off = (float)(t - 80);
            if (fabsf(off) <= radf) { float z = off / sigma; w = expf(-0.5f * z * z); }
        }
        wl[t] = w;
    }
    __syncthreads();
    if (t < 64) {
        float v = wl[t] + wl[t + 64] + wl[t + 128];
        #pragma unroll
        for (int o = 32; o > 0; o >>= 1) v += __shfl_down(v, o);
        if (t == 0) red[0] = 1.0f / v;
    }
    __syncthreads();
    float rs = red[0];
    if (t < 161) wl[t] *= rs;
    __syncthreads();
    return (int)radf;
}

__global__ __launch_bounds__(256) void vblur_nt(const float* __restrict__ in,
                                                float* __restrict__ out,
                                                const float* __restrict__ sigmas,
                                                const int* __restrict__ steps) {
    __shared__ float wl[192];
    __shared__ float red[1];
    int bid = blockIdx.x;
    int b = bid >> 4, i0 = (bid & 15) * 16;
    int rad = make_weights161(b, sigmas, steps, wl, red);
    int j = threadIdx.x;
    const float* inb = in + (size_t)b * WDIM * WDIM;
    float acc[16];
    #pragma unroll
    for (int ii = 0; ii < 16; ++ii) acc[ii] = 0.0f;
    for (int u = -rad; u <= rad; ++u) {
        float w = wl[80 + u];
        #pragma unroll
        for (int ii = 0; ii < 16; ++ii)
            acc[ii] = fmaf(w, inb[reflect(i0 + ii + u) * WDIM + j], acc[ii]);
    }
    #pragma unroll
    for (int ii = 0; ii < 16; ++ii)
        out[((size_t)b * WDIM + (i0 + ii)) * WDIM + j] = acc[ii];
}

__global__ __launch_bounds__(256) void hblur_inplace(float* __restrict__ buf,
                                                     const float* __restrict__ sigmas,
                                                     const int* __restrict__ steps) {
    __shared__ float wl[192];
    __shared__ float red[1];
    __shared__ float rp[WDIM + 160];
    int bid = blockIdx.x;
    int b = bid >> 8, i = bid & 255;
    float* row = buf + ((size_t)b * WDIM + i) * WDIM;
    int t = threadIdx.x;
    for (int s = t; s < WDIM + 160; s += 256) rp[s] = row[reflect(s - 80)];
    int rad = make_weights161(b, sigmas, steps, wl, red);
    float acc = 0.0f;
    for (int u = -rad; u <= rad; ++u) acc = fmaf(wl[80 + u], rp[80 + t + u], acc);
    row[t] = acc;
}
// --------------------------------------------------------------------------------

extern "C" void kernel_launch(void* const* d_in, const int* in_sizes, int n_in,
                              void* d_out, int out_size, void* d_ws, size_t ws_size,
                              hipStream_t stream) {
    const float* x     = (const float*)d_in[0];
    const float* sig   = (const float*)d_in[1];
    const int*   steps = (const int*)d_in[2];
    float* out = (float*)d_out;

    const size_t need = (size_t)WOFF + (size_t)NSIG * WDIM * WDIM * 2;
    if (ws_size >= need) {
        int* q = (int*)d_ws;
        _Float16* Wg = (_Float16*)((char*)d_ws + WOFF);
        build_w<<<NSIG, 256, 0, stream>>>(sig, Wg);
        build_queue<<<1, 256, 0, stream>>>(sig, steps, q);
        blur_mfma<true><<<NBAND, 256, 0, stream>>>(x, out, sig, steps, q, Wg);
    } else {
        vblur_nt<<<NSAMP * 16, 256, 0, stream>>>(x, out, sig, steps);
        hblur_inplace<<<NSAMP * WDIM, 256, 0, stream>>>(out, sig, steps);
    }
}

// Round 14
// 84.529 us; speedup vs baseline: 2.1319x; 1.3958x over previous
//
#include <hip/hip_runtime.h>

#define WDIM  256
#define NSAMP 512
#define NSIG  32
#define RB    64                 // band rows per block-task
#define NBAND 2048
#define QOFF  16                 // ints; queue table q[QOFF..]
#define WOFF  65536              // byte offset of W matrices inside d_ws

typedef float    f32x4 __attribute__((ext_vector_type(4)));
typedef _Float16 f16x8 __attribute__((ext_vector_type(8)));

__device__ __forceinline__ int reflect(int q) {
    q = (q < 0) ? (-q - 1) : q;
    return (q >= WDIM) ? (2 * WDIM - 1 - q) : q;
}

// ---- kernel 1: build 32 reflect-folded banded weight matrices (f16) ----
// W_s[i][r] = wz(r-i) + wz(-r-1-i) + wz(511-r-i), wz = masked+normalized gaussian.
// Grid (NSIG, 8): blockIdx.y covers 4 of the 32 row-octets.
__global__ __launch_bounds__(256) void build_w(const float* __restrict__ sigmas,
                                               _Float16* __restrict__ Wg) {
    __shared__ float wl[161];
    __shared__ float red;
    int s = blockIdx.x, t = threadIdx.x;
    float sigma = sigmas[s];
    float radf = floorf(4.0f * sigma + 0.5f);
    if (t < 161) {
        float off = (float)(t - 80);
        float w = 0.0f;
        if (fabsf(off) <= radf) { float z = off / sigma; w = expf(-0.5f * z * z); }
        wl[t] = w;
    }
    __syncthreads();
    if (t < 64) {
        float v = wl[t] + wl[t + 64] + (t < 33 ? wl[t + 128] : 0.0f);
        #pragma unroll
        for (int o = 32; o > 0; o >>= 1) v += __shfl_down(v, o);
        if (t == 0) red = 1.0f / v;
    }
    __syncthreads();
    float rs = red;
    int i = t;
    _Float16* wrow = Wg + ((size_t)s << 16) + (i << 8);
    for (int rq = blockIdx.y * 4; rq < blockIdx.y * 4 + 4; ++rq) {
        f16x8 v;
        #pragma unroll
        for (int j = 0; j < 8; ++j) {
            int r = rq * 8 + j;
            int d1 = r - i, d2 = -r - 1 - i, d3 = 511 - r - i;
            float w = 0.0f;
            if (d1 >= -80 && d1 <= 80) w += wl[d1 + 80];
            if (d2 >= -80)             w += wl[d2 + 80];
            if (d3 <= 80)              w += wl[d3 + 80];
            v[j] = (_Float16)(w * rs);
        }
        *(f16x8*)(wrow + rq * 8) = v;
    }
}

// ---- kernel 2: striped-LPT static queue (balance across XCDs + locality) ----
__global__ void build_queue(const float* __restrict__ sigmas,
                            const int* __restrict__ steps,
                            int* __restrict__ q) {
    __shared__ int hist[32];
    __shared__ int base[32];
    int t = threadIdx.x;
    if (t < 32) hist[t] = 0;
    __syncthreads();
    int nb2[2];
    #pragma unroll
    for (int k = 0; k < 2; ++k) {
        int s = t + 256 * k;
        float sigma = sigmas[steps[s]];
        int rad = (int)floorf(4.0f * sigma + 0.5f);
        nb2[k] = (2 * rad + 15) >> 3;
        atomicAdd(&hist[nb2[k]], 1);
    }
    __syncthreads();
    if (t == 0) {
        int acc = 0;
        for (int bin = 31; bin >= 0; --bin) { base[bin] = acc; acc += hist[bin]; }
    }
    __syncthreads();
    #pragma unroll
    for (int k = 0; k < 2; ++k) {
        int s = t + 256 * k;
        int r = atomicAdd(&base[nb2[k]], 1);
        int x = r & 7;
        int p = r >> 3;
        #pragma unroll
        for (int jb = 0; jb < 4; ++jb)
            q[QOFF + (((p << 2) + jb) << 3) + x] = (s << 2) | jb;
    }
}

// ---- kernel 3: fused MFMA blur, barrier-free phase V. ----
// Phase V: Y = W_band X. A-frag = W rows (direct 16B global). B-frag = X
//          column-slices via 8 direct dword loads + cvt (no LDS, no barriers).
//          Y -> swizzled LDS (f16).
// Phase H: Z = Y W^T. A-frag = Y from LDS, B-frag = W rows direct. f32 out.
template <bool QUEUED>
__global__ __launch_bounds__(256, 4) void blur_mfma(const float* __restrict__ in,
                                                    float* __restrict__ out,
                                                    const float* __restrict__ sigmas,
                                                    const int* __restrict__ steps,
                                                    const int* __restrict__ q,
                                                    const _Float16* __restrict__ Wg) {
    __shared__ alignas(16) _Float16 YL[RB * WDIM];    // 32KB: Y[i][c] swizzled

    int e;
    if constexpr (QUEUED) e = q[QOFF + blockIdx.x];
    else { int bid = blockIdx.x; e = (bid & 7) * (NBAND / 8) + (bid >> 3); }
    int b  = e >> 2;
    int r0 = (e & 3) * RB;

    int s = steps[b];
    float sigma = sigmas[s];
    int rad = (int)floorf(4.0f * sigma + 0.5f);
    const _Float16* Wm = Wg + ((size_t)s << 16);
    const float*    Xb = in + ((size_t)b << 16);

    int ln = threadIdx.x & 63, wv = threadIdx.x >> 6;
    int lm = ln & 15, lq = ln >> 4;

    // ---------------- Phase V: Y[i][c] = sum_r W[r0+i][r] X[r][c] ----------------
    // Wave wv owns c in [wv*64, wv*64+64). No LDS, no barriers.
    f32x4 acc[4][4];
    #pragma unroll
    for (int mt = 0; mt < 4; ++mt)
        #pragma unroll
        for (int nt = 0; nt < 4; ++nt) acc[mt][nt] = (f32x4)0.0f;

    int kt0 = max(0, r0 - rad) >> 5;
    int kt1 = min(WDIM - 1, r0 + RB - 1 + rad) >> 5;

    for (int kt = kt0; kt <= kt1; ++kt) {
        f16x8 af[4];
        #pragma unroll
        for (int mt = 0; mt < 4; ++mt)
            af[mt] = *(const f16x8*)(Wm + (size_t)(r0 + mt * 16 + lm) * WDIM + (kt << 5) + lq * 8);
        #pragma unroll
        for (int nt = 0; nt < 4; ++nt) {
            // B-frag: X[kt*32 + lq*8 + jj][c], jj=0..7  (8 direct dword loads)
            const float* xp = Xb + (size_t)((kt << 5) + lq * 8) * WDIM + wv * 64 + nt * 16 + lm;
            float xv[8];
            #pragma unroll
            for (int jj = 0; jj < 8; ++jj) xv[jj] = xp[jj * WDIM];
            f16x8 bf;
            #pragma unroll
            for (int jj = 0; jj < 8; ++jj) bf[jj] = (_Float16)xv[jj];
            #pragma unroll
            for (int mt = 0; mt < 4; ++mt)
                acc[mt][nt] = __builtin_amdgcn_mfma_f32_16x16x32_f16(af[mt], bf, acc[mt][nt], 0, 0, 0);
        }
    }

    // write Y to swizzled LDS: D layout row=(lq*4+g), col=lm per 16x16 tile
    #pragma unroll
    for (int mt = 0; mt < 4; ++mt)
        #pragma unroll
        for (int nt = 0; nt < 4; ++nt)
            #pragma unroll
            for (int g = 0; g < 4; ++g) {
                int i = mt * 16 + lq * 4 + g;
                int c = wv * 64 + nt * 16 + lm;
                YL[(i << 8) + (c ^ ((i & 7) << 3))] = (_Float16)acc[mt][nt][g];
            }
    __syncthreads();

    // ---------------- Phase H: Z[i][j] = sum_c Y[i][c] W[j][c] ----------------
    f32x4 hac[4][4];
    #pragma unroll
    for (int mt = 0; mt < 4; ++mt)
        #pragma unroll
        for (int nt = 0; nt < 4; ++nt) hac[mt][nt] = (f32x4)0.0f;

    int jlo = wv * 64;
    int hk0 = max(0, jlo - rad) >> 5;
    int hk1 = min(WDIM - 1, jlo + 63 + rad) >> 5;

    for (int kt = hk0; kt <= hk1; ++kt) {
        f16x8 af[4], bf[4];
        #pragma unroll
        for (int mt = 0; mt < 4; ++mt) {
            int i = mt * 16 + lm;
            int c0 = (kt << 5) + lq * 8;
            af[mt] = *(const f16x8*)&YL[(i << 8) + (c0 ^ ((i & 7) << 3))];
        }
        #pragma unroll
        for (int nt = 0; nt < 4; ++nt)
            bf[nt] = *(const f16x8*)(Wm + (size_t)(jlo + nt * 16 + lm) * WDIM + (kt << 5) + lq * 8);
        #pragma unroll
        for (int mt = 0; mt < 4; ++mt)
            #pragma unroll
            for (int nt = 0; nt < 4; ++nt)
                hac[mt][nt] = __builtin_amdgcn_mfma_f32_16x16x32_f16(af[mt], bf[nt], hac[mt][nt], 0, 0, 0);
    }

    float* ob = out + ((size_t)b << 16);
    #pragma unroll
    for (int mt = 0; mt < 4; ++mt)
        #pragma unroll
        for (int nt = 0; nt < 4; ++nt)
            #pragma unroll
            for (int g = 0; g < 4; ++g)
                ob[(size_t)(r0 + mt * 16 + lq * 4 + g) * WDIM + jlo + nt * 16 + lm] = hac[mt][nt][g];
}

// ---------- fallback path (only if ws too small; needs no workspace) ----------
__device__ __forceinline__ int make_weights161(int b, const float* __restrict__ sigmas,
                                               const int* __restrict__ steps,
                                               float* wl, float* red) {
    int t = threadIdx.x;
    float sigma = sigmas[steps[b]];
    float radf = floorf(4.0f * sigma + 0.5f);
    if (t < 192) {
        float w = 0.0f;
        if (t < 161) {
            float off = (float)(t - 80);
            if (fabsf(off) <= radf) { float z = off / sigma; w = expf(-0.5f * z * z); }
        }
        wl[t] = w;
    }
    __syncthreads();
    if (t < 64) {
        float v = wl[t] + wl[t + 64] + wl[t + 128];
        #pragma unroll
        for (int o = 32; o > 0; o >>= 1) v += __shfl_down(v, o);
        if (t == 0) red[0] = 1.0f / v;
    }
    __syncthreads();
    float rs = red[0];
    if (t < 161) wl[t] *= rs;
    __syncthreads();
    return (int)radf;
}

__global__ __launch_bounds__(256) void vblur_nt(const float* __restrict__ in,
                                                float* __restrict__ out,
                                                const float* __restrict__ sigmas,
                                                const int* __restrict__ steps) {
    __shared__ float wl[192];
    __shared__ float red[1];
    int bid = blockIdx.x;
    int b = bid >> 4, i0 = (bid & 15) * 16;
    int rad = make_weights161(b, sigmas, steps, wl, red);
    int j = threadIdx.x;
    const float* inb = in + (size_t)b * WDIM * WDIM;
    float acc[16];
    #pragma unroll
    for (int ii = 0; ii < 16; ++ii) acc[ii] = 0.0f;
    for (int u = -rad; u <= rad; ++u) {
        float w = wl[80 + u];
        #pragma unroll
        for (int ii = 0; ii < 16; ++ii)
            acc[ii] = fmaf(w, inb[reflect(i0 + ii + u) * WDIM + j], acc[ii]);
    }
    #pragma unroll
    for (int ii = 0; ii < 16; ++ii)
        out[((size_t)b * WDIM + (i0 + ii)) * WDIM + j] = acc[ii];
}

__global__ __launch_bounds__(256) void hblur_inplace(float* __restrict__ buf,
                                                     const float* __restrict__ sigmas,
                                                     const int* __restrict__ steps) {
    __shared__ float wl[192];
    __shared__ float red[1];
    __shared__ float rp[WDIM + 160];
    int bid = blockIdx.x;
    int b = bid >> 8, i = bid & 255;
    float* row = buf + ((size_t)b * WDIM + i) * WDIM;
    int t = threadIdx.x;
    for (int s = t; s < WDIM + 160; s += 256) rp[s] = row[reflect(s - 80)];
    int rad = make_weights161(b, sigmas, steps, wl, red);
    float acc = 0.0f;
    for (int u = -rad; u <= rad; ++u) acc = fmaf(wl[80 + u], rp[80 + t + u], acc);
    row[t] = acc;
}
// --------------------------------------------------------------------------------

extern "C" void kernel_launch(void* const* d_in, const int* in_sizes, int n_in,
                              void* d_out, int out_size, void* d_ws, size_t ws_size,
                              hipStream_t stream) {
    const float* x     = (const float*)d_in[0];
    const float* sig   = (const float*)d_in[1];
    const int*   steps = (const int*)d_in[2];
    float* out = (float*)d_out;

    const size_t need = (size_t)WOFF + (size_t)NSIG * WDIM * WDIM * 2;
    if (ws_size >= need) {
        int* q = (int*)d_ws;
        _Float16* Wg = (_Float16*)((char*)d_ws + WOFF);
        build_w<<<dim3(NSIG, 8), 256, 0, stream>>>(sig, Wg);
        build_queue<<<1, 256, 0, stream>>>(sig, steps, q);
        blur_mfma<true><<<NBAND, 256, 0, stream>>>(x, out, sig, steps, q, Wg);
    } else {
        vblur_nt<<<NSAMP * 16, 256, 0, stream>>>(x, out, sig, steps);
        hblur_inplace<<<NSAMP * WDIM, 256, 0, stream>>>(out, sig, steps);
    }
}